// Round 16
// baseline (83.146 us; speedup 1.0000x reference)
//
#include <hip/hip_runtime.h>

// Shapes (fixed): T=8, S=512, B=8, D=512, H=8, hd=64, BH=64, NE=32, NI=64.
// out: (64, 512, 512) f32.
//
// Math reduction: sum_p telescopes to (sum_t Q_t)(sum_t K_t)^T * scale, so
//   p = (Xsum@Wq^T + 8 bq)(Xsum@Wk^T + 8 bk)^T / 64   (per bh batch, hd=64)
// The 1/64 is folded into Q at projection time.
//
// Q/K are stored in MFMA-FRAGMENT ORDER: [bh][blk16][half][lane][16B], so
// k_attn operand loads are fully-coalesced 1KB dwordx4 reads. The SAME
// layout serves both A- and B-operands.
//
// k_attn computes P^T tiles: mfma(A=K_block, B=Q) -> D[col=q=lane&15,
// row=k=(lane>>4)*4+j]. Each lane holds 4 CONSECUTIVE k for one q-row:
// f32x4 nt stores, scalar tm1/cj/rowsum, lane-local n-distributed fac.
//
// R15->R16: (a) 2 q-blocks per block (1024 blocks, unroll-1 loop): LUT
// stage + launch/retire amortized 2x, s_part[2] double-buffered so only 3
// barriers per 2 q-blocks; (b) launch_bounds(256,5): R15's lean epilogue
// (~92 regs incl 32 AGPR) fits the 102-reg budget -> 5 blocks/CU (20
// waves/CU, +25% latency hiding). TRIPWIRE: FETCH>15MB or WRITE>95MB =>
// spilled => revert to (256,4) keeping the loop.
//
// REGISTER RULE (R4/R6/R8/R14): VGPR+AGPR one budget. acc[8] only.

#define T_  8
#define NE_ 32
#define NI_ 64

#define LUT_N   2048
#define LUT_LO  -20.0f
#define LUT_HI  3.0f
#define LUT_INVW (LUT_N / (LUT_HI - LUT_LO))     // 2048/23
#define LUT_W    ((LUT_HI - LUT_LO) / LUT_N)

typedef __attribute__((ext_vector_type(8))) short bf16x8;
typedef __attribute__((ext_vector_type(4))) float f32x4;
typedef __attribute__((ext_vector_type(4))) unsigned int u32x4;

// workspace layout, in ushort elements
#define XS_OFF 0u        // Xsum bf16 (4096 x 512)
#define WQ_OFF 2097152u  // Wq bf16 (512 x 512)
#define WK_OFF 2359296u  // Wk bf16
#define QB_OFF 2621440u  // Q bf16 frag-order (64*32*2*1024B), pre-scaled 1/64
#define KB_OFF 4718592u  // K bf16 frag-order
#define LUT_OFF 6815744u // float2 lut[2048] = 16 KB (index-space chord a',b')

__device__ inline unsigned short f2bf(float f) {
  union { float f; unsigned u; } v; v.f = f;
  unsigned r = v.u + 0x7FFFu + ((v.u >> 16) & 1u);
  return (unsigned short)(r >> 16);
}

__device__ inline void gload16(const void* g, void* l) {
  __builtin_amdgcn_global_load_lds(
      (const __attribute__((address_space(1))) void*)g,
      (__attribute__((address_space(3))) void*)l, 16, 0, 0);
}

// XOR-swizzled LDS read (k_proj GEMM tiles): 128B rows, slot ^ (row&7)
__device__ inline bf16x8 lds_read_swz(const unsigned short* base, int row, int byteoff) {
  int addr = row * 128 + (byteoff ^ ((row & 7) << 4));
  return *(const bf16x8*)((const char*)base + addr);
}

__device__ inline float expmlp_exact(float t, const float* __restrict__ w1,
                                     const float* __restrict__ b1,
                                     const float* __restrict__ w2, float b2) {
  float a = b2;
#pragma unroll
  for (int n = 0; n < NE_; n++) a += w2[n] * fmaxf(t * w1[n] + b1[n], 0.0f);
  return a;
}

// ---------------------------------------------------------------------------
// Kernel 1: Xsum = sum_t sx[t] (f32->bf16, nt loads), Wq/Wk casts, chord LUT.
__global__ __launch_bounds__(256) void k_pre(
    const float* __restrict__ sx, const float* __restrict__ wq,
    const float* __restrict__ wk, const float* __restrict__ ew1,
    const float* __restrict__ eb1, const float* __restrict__ ew2,
    const float* __restrict__ eb2p,
    unsigned short* __restrict__ xs, unsigned short* __restrict__ wqb,
    unsigned short* __restrict__ wkb, float2* __restrict__ lut) {
  int bx = blockIdx.x, tid = threadIdx.x;
  if (bx < 2048) {
    size_t i = ((size_t)bx * 256 + tid) * 4;
    f32x4 a = __builtin_nontemporal_load((const f32x4*)(sx + i));
#pragma unroll
    for (int t = 1; t < T_; t++) {
      f32x4 v = __builtin_nontemporal_load((const f32x4*)(sx + (size_t)t * 2097152 + i));
      a += v;
    }
    ushort4 o; o.x = f2bf(a[0]); o.y = f2bf(a[1]); o.z = f2bf(a[2]); o.w = f2bf(a[3]);
    *(ushort4*)(xs + i) = o;
  } else if (bx < 2560) {
    const float* src = (bx < 2304) ? wq : wk;
    unsigned short* dst = (bx < 2304) ? wqb : wkb;
    int base = (bx < 2304) ? 2048 : 2304;
    size_t i = ((size_t)(bx - base) * 256 + tid) * 4;
    float4 a = *(const float4*)(src + i);
    ushort4 o; o.x = f2bf(a.x); o.y = f2bf(a.y); o.z = f2bf(a.z); o.w = f2bf(a.w);
    *(ushort4*)(dst + i) = o;
  } else {
    // index-space chord LUT: xu(u) = a'*u + b' on bucket i (u in [i, i+1]);
    // a' = f(t_{i+1})-f(t_i), b' = f(t_i) - a'*i. Edges shared -> continuity.
    int i = (bx - 2560) * 256 + tid;
    if (i < LUT_N) {
      float b2 = eb2p[0];
      float tl = fmaf((float)i, LUT_W, LUT_LO);
      float th = fmaf((float)(i + 1), LUT_W, LUT_LO);
      float el = expmlp_exact(tl, ew1, eb1, ew2, b2);
      float eh = expmlp_exact(th, ew1, eb1, ew2, b2);
      float ap = eh - el;
      float bp = fmaf(-ap, (float)i, el);
      lut[i] = make_float2(ap, bp);
    }
  }
}

// ---------------------------------------------------------------------------
// Kernel 2: Y = Xsum(4096x512) @ W^T + 8*bias -> bf16 frag-order layout.
// z=0 (Q) additionally scaled by 1/64.  grid (64,4,2) = 512 blocks
// (2 blocks/CU), 256 thr, 64x128 tile: 4 waves of 32x64. LDS 24KB.
// Output restaged via LDS (reuses Bs) -> coalesced 16B stores.
__global__ __launch_bounds__(256, 2) void k_proj(
    const unsigned short* __restrict__ xs, const unsigned short* __restrict__ wb,
    const float* __restrict__ bq, const float* __restrict__ bk,
    unsigned short* __restrict__ outb) {
  __shared__ unsigned short As[64 * 64];    // 8 KB
  __shared__ unsigned short Bs[128 * 64];   // 16 KB (reused as Os)
  int tid = threadIdx.x;
  int lane = tid & 63, w = tid >> 6;
  int r0 = blockIdx.x * 64;
  int c0 = blockIdx.y * 128;
  int z = blockIdx.z;
  const unsigned short* W = wb + (size_t)z * 262144;
  const float* bias = z ? bk : bq;
  unsigned short* dst = outb + (size_t)z * 2097152;
  float sc = z ? 1.0f : (1.0f / 64.0f);

  int rgrp = lane >> 4, cl = lane & 15;
  int r0w = (w >> 1) * 32, c0w = (w & 1) * 64;

  f32x4 acc[2][4];
  f32x4 zero = {0.f, 0.f, 0.f, 0.f};
#pragma unroll
  for (int m = 0; m < 2; m++)
#pragma unroll
    for (int n = 0; n < 4; n++) acc[m][n] = zero;

  int rl = lane >> 3, slot = lane & 7;

  for (int kt = 0; kt < 8; kt++) {
    int k0 = kt * 64;
#pragma unroll
    for (int i = 0; i < 2; i++) {
      int chunk = w * 2 + i;
      int r = chunk * 8 + rl;
      int sw = (slot ^ (r & 7)) * 8;
      gload16(xs + (size_t)(r0 + r) * 512 + k0 + sw, (char*)As + chunk * 1024);
    }
#pragma unroll
    for (int i = 0; i < 4; i++) {
      int chunk = w * 4 + i;
      int r = chunk * 8 + rl;
      int sw = (slot ^ (r & 7)) * 8;
      gload16(W + (size_t)(c0 + r) * 512 + k0 + sw, (char*)Bs + chunk * 1024);
    }
    __syncthreads();
#pragma unroll
    for (int kb = 0; kb < 2; kb++) {
      bf16x8 af[2], bfr[4];
#pragma unroll
      for (int m = 0; m < 2; m++) af[m] = lds_read_swz(As, r0w + 16 * m + cl, kb * 64 + rgrp * 16);
#pragma unroll
      for (int n = 0; n < 4; n++) bfr[n] = lds_read_swz(Bs, c0w + 16 * n + cl, kb * 64 + rgrp * 16);
#pragma unroll
      for (int m = 0; m < 2; m++)
#pragma unroll
        for (int n = 0; n < 4; n++)
          acc[m][n] = __builtin_amdgcn_mfma_f32_16x16x32_bf16(af[m], bfr[n], acc[m][n], 0, 0, 0);
    }
    __syncthreads();
  }

  // stage: +8*bias, scale, cast -> Os (=Bs) in frag-order
  unsigned short* Os = Bs;
#pragma unroll
  for (int n = 0; n < 4; n++) {
    int cgl = c0w + 16 * n + cl;               // [0,128)
    float bv = 8.0f * bias[c0 + cgl];
    int hl = cgl >> 6, dh = cgl & 63;
    int hh = dh >> 5, rg2 = (dh >> 3) & 3, jj = dh & 7;
#pragma unroll
    for (int m = 0; m < 2; m++) {
#pragma unroll
      for (int j = 0; j < 4; j++) {
        int rgl = r0w + 16 * m + rgrp * 4 + j;  // [0,64)
        int b = rgl & 7, clsl = rgl >> 3;       // [0,8)
        Os[((((b * 2 + hl) * 2 + hh) * 4 + rg2) * 8 + clsl) * 8 + jj] =
            f2bf((acc[m][n][j] + bv) * sc);
      }
    }
  }
  __syncthreads();

  // coalesced store: 1024 x 16B units
  int cb = blockIdx.x >> 1;
  int clsbase = (blockIdx.x & 1) * 8;
  int h0 = c0 >> 6;
#pragma unroll
  for (int i2 = 0; i2 < 4; i2++) {
    int unit = i2 * 256 + tid;                  // [b:3][hl:1][hh:1][rg2:2][clsl:3]
    int clsl = unit & 7, rg2 = (unit >> 3) & 3, hh = (unit >> 5) & 1;
    int hl = (unit >> 6) & 1, b = unit >> 7;
    int bh = b * 8 + h0 + hl;
    size_t du = ((size_t)((bh * 32 + cb) * 2 + hh)) * 512 + (rg2 * 16 + clsbase + clsl) * 8;
    *(u32x4*)(dst + du) = *(const u32x4*)(Os + unit * 8);
  }
}

// ---------------------------------------------------------------------------
// Kernel 3: per block: TWO consecutive 16-row q-blocks of one bh (unroll-1
// loop). P^T tiles via mfma(K, Q), chord LUT epilogue, f32x4 nt stores.
// grid 1024 x 256 thr (4 waves); wave w = 128 k-col strip, acc[8].
// launch_bounds(256,5): 102-reg budget, ~92 used -> 5 blocks/CU.
// s_part double-buffered -> 3 barriers per 2 q-blocks. XCD-chunked blockIdx.
__global__ __launch_bounds__(256, 5) void k_attn(
    const unsigned short* __restrict__ qb, const unsigned short* __restrict__ kb,
    const float2* __restrict__ lutg,
    const float* __restrict__ iw1, const float* __restrict__ ib1,
    const float* __restrict__ iw2, const float* __restrict__ ib2p,
    float* __restrict__ out) {
  __shared__ float2 Lut[LUT_N];   // 16 KB
  __shared__ float s_part[2][4][16];

  int tid = threadIdx.x;
  int lane = tid & 63, w = tid >> 6;   // w = 128-k-col strip
  int i = blockIdx.x;
  int xcd = i & 7, j2 = i >> 3;        // j2 in [0,128)
  int bh = xcd * 8 + (j2 >> 4);
  int rb0 = (j2 & 15) * 2;             // first of two consecutive q-blocks
  int rgrp = lane >> 4, cl = lane & 15;

  // stage LUT once per block: 16 KB via gload16 (4 waves x 4 chunks of 1KB);
  // published by the iter-0 barrier AFTER the MFMA phase.
#pragma unroll
  for (int c = 0; c < 4; c++) {
    int chunk = w * 4 + c;
    gload16((const char*)lutg + chunk * 1024 + lane * 16, (char*)Lut + chunk * 1024);
  }

  const char* Kbase = (const char*)kb + (size_t)(bh * 32) * 2048;
  const float C0 = -LUT_LO * LUT_INVW;
  float b2 = ib2p[0];
  f32x4 zero = {0.f, 0.f, 0.f, 0.f};

#pragma unroll 1
  for (int it = 0; it < 2; ++it) {
    int rb = rb0 + it;
    // Q fragments (B-operand) for this q-block's 16 rows (1KB coalesced)
    const char* Qb = (const char*)qb + (size_t)((bh * 32 + rb) * 2) * 1024;
    bf16x8 qF0 = *(const bf16x8*)(Qb + lane * 16);
    bf16x8 qF1 = *(const bf16x8*)(Qb + 1024 + lane * 16);

    // tmax from k-block 0: D[col=q=cl, row=k]; P[0][q] in lane q, reg 0
    float tm1;
    {
      bf16x8 k0 = *(const bf16x8*)(Kbase + lane * 16);
      bf16x8 k1 = *(const bf16x8*)(Kbase + 1024 + lane * 16);
      f32x4 p0 = __builtin_amdgcn_mfma_f32_16x16x32_bf16(k0, qF0, zero, 0, 0, 0);
      p0 = __builtin_amdgcn_mfma_f32_16x16x32_bf16(k1, qF1, p0, 0, 0, 0);
      tm1 = __shfl(p0[0], cl) - 1.0f;
    }

    f32x4 acc[8];
#pragma unroll
    for (int f = 0; f < 8; f++) {
      const char* Kb = Kbase + (size_t)(w * 8 + f) * 2048;
      bf16x8 k0 = *(const bf16x8*)(Kb + lane * 16);
      bf16x8 k1 = *(const bf16x8*)(Kb + 1024 + lane * 16);
      acc[f] = __builtin_amdgcn_mfma_f32_16x16x32_bf16(k0, qF0, zero, 0, 0, 0);
      acc[f] = __builtin_amdgcn_mfma_f32_16x16x32_bf16(k1, qF1, acc[f], 0, 0, 0);
    }

    if (it == 0) __syncthreads();  // LUT publish (uniform branch)

    // u0 = p*INVW + cj; u0>0 <=> tp>-20; u = clamp(u0,0,N); xu = a'*u + b'
    float cj = fmaf(-tm1, LUT_INVW, C0);
    float rowsum = 0.0f;
#pragma unroll
    for (int f = 0; f < 8; f++) {
#pragma unroll
      for (int j = 0; j < 4; j++) {
        float u0 = fmaf(acc[f][j], LUT_INVW, cj);
        float u = fminf(fmaxf(u0, 0.0f), (float)LUT_N);    // v_med3
        int bi = (int)u;
        bi = min(bi, LUT_N - 1);
        float2 ab = Lut[bi];
        float xu = fmaf(ab.x, u, ab.y);
        xu = (u0 > 0.0f) ? xu : 0.0f;
        acc[f][j] = xu;
        rowsum += xu;
      }
    }

    // lanes {cl, cl+16, cl+32, cl+48} share q-row cl
    rowsum += __shfl_xor(rowsum, 16);
    rowsum += __shfl_xor(rowsum, 32);
    if (lane < 16) s_part[it][w][lane] = rowsum;
    __syncthreads();

    float part = s_part[it][0][cl] + s_part[it][1][cl] +
                 s_part[it][2][cl] + s_part[it][3][cl];

    // n-distributed inv-MLP: lane covers 16 n-terms (chunk = rgrp) of row cl
    float a = 0.0f;
#pragma unroll
    for (int nn = 0; nn < 16; nn++) {
      int n = rgrp * 16 + nn;
      a += iw2[n] * fmaxf(part * iw1[n] + ib1[n], 0.0f);
    }
    a += __shfl_xor(a, 16);
    a += __shfl_xor(a, 32);
    float pinv = a + b2;
    float pp2 = part * pinv;
    float bb = 0.0f;
#pragma unroll
    for (int nn = 0; nn < 16; nn++) {
      int n = rgrp * 16 + nn;
      bb += iw2[n] * fmaxf(pp2 * iw1[n] + ib1[n], 0.0f);
    }
    bb += __shfl_xor(bb, 16);
    bb += __shfl_xor(bb, 32);
    float pinv2 = bb + b2;
    float fac = (pp2 > 1.5f) ? pinv * pinv2 : pinv;

    // f32x4 nt stores: row = q = cl, cols w*128 + f*16 + rgrp*4
    float* outb = out + ((size_t)(bh * 512 + rb * 16 + cl)) * 512 + w * 128 + rgrp * 4;
#pragma unroll
    for (int f = 0; f < 8; f++) {
      f32x4 v;
#pragma unroll
      for (int j = 0; j < 4; j++) v[j] = acc[f][j] * fac;
      __builtin_nontemporal_store(v, (f32x4*)(outb + f * 16));
    }
  }
}

extern "C" void kernel_launch(void* const* d_in, const int* in_sizes, int n_in,
                              void* d_out, int out_size, void* d_ws, size_t ws_size,
                              hipStream_t stream) {
  (void)in_sizes; (void)n_in; (void)out_size; (void)ws_size;
  const float* sx  = (const float*)d_in[0];
  const float* wq  = (const float*)d_in[1];
  const float* wk  = (const float*)d_in[2];
  const float* bq  = (const float*)d_in[3];
  const float* bk  = (const float*)d_in[4];
  const float* ew1 = (const float*)d_in[5];
  const float* eb1 = (const float*)d_in[6];
  const float* ew2 = (const float*)d_in[7];
  const float* eb2 = (const float*)d_in[8];
  const float* iw1 = (const float*)d_in[9];
  const float* ib1 = (const float*)d_in[10];
  const float* iw2 = (const float*)d_in[11];
  const float* ib2 = (const float*)d_in[12];
  unsigned short* wsu = (unsigned short*)d_ws;
  float2* lut = (float2*)(wsu + LUT_OFF);
  float* out = (float*)d_out;

  k_pre<<<2568, 256, 0, stream>>>(sx, wq, wk, ew1, eb1, ew2, eb2,
                                  wsu + XS_OFF, wsu + WQ_OFF, wsu + WK_OFF, lut);
  k_proj<<<dim3(64, 4, 2), 256, 0, stream>>>(wsu + XS_OFF, wsu + WQ_OFF, bq, bk, wsu + QB_OFF);
  k_attn<<<1024, 256, 0, stream>>>(wsu + QB_OFF, wsu + KB_OFF, lut,
                                   iw1, ib1, iw2, ib2, out);
}

// Round 17
// 69.535 us; speedup vs baseline: 1.1957x; 1.1957x over previous
//
#include <hip/hip_runtime.h>

// Shapes (fixed): T=8, S=512, B=8, D=512, H=8, hd=64, BH=64, NE=32, NI=64.
// out: (64, 512, 512) f32.
//
// Math reduction: sum_p telescopes to (sum_t Q_t)(sum_t K_t)^T * scale, so
//   p = (Xsum@Wq^T + 8 bq)(Xsum@Wk^T + 8 bk)^T / 64   (per bh batch, hd=64)
// The 1/64 is folded into Q at projection time.
//
// Q/K are stored in MFMA-FRAGMENT ORDER: [bh][blk16][half][lane][16B], so
// k_attn operand loads are fully-coalesced 1KB dwordx4 reads. The SAME
// layout serves both A- and B-operands.
//
// k_attn computes P^T tiles: mfma(A=K_block, B=Q) -> D[col=q=lane&15,
// row=k=(lane>>4)*4+j]. Each lane holds 4 CONSECUTIVE k for one q-row:
// f32x4 nt stores, scalar tm1/cj/rowsum, lane-local n-distributed fac.
//
// R16->R17: launch bound reverted (256,5)->(256,4). FINAL REGISTER RULE:
// three spills at budget<=102 (R8, R14-analog, R16: VGPR squeezed to 48,
// FETCH 80MB, WRITE 156MB) vs three clean runs at budget 128. The 2-q-block
// amortization loop is kept (no cross-iteration live state).

#define T_  8
#define NE_ 32
#define NI_ 64

#define LUT_N   2048
#define LUT_LO  -20.0f
#define LUT_HI  3.0f
#define LUT_INVW (LUT_N / (LUT_HI - LUT_LO))     // 2048/23
#define LUT_W    ((LUT_HI - LUT_LO) / LUT_N)

typedef __attribute__((ext_vector_type(8))) short bf16x8;
typedef __attribute__((ext_vector_type(4))) float f32x4;
typedef __attribute__((ext_vector_type(4))) unsigned int u32x4;

// workspace layout, in ushort elements
#define XS_OFF 0u        // Xsum bf16 (4096 x 512)
#define WQ_OFF 2097152u  // Wq bf16 (512 x 512)
#define WK_OFF 2359296u  // Wk bf16
#define QB_OFF 2621440u  // Q bf16 frag-order (64*32*2*1024B), pre-scaled 1/64
#define KB_OFF 4718592u  // K bf16 frag-order
#define LUT_OFF 6815744u // float2 lut[2048] = 16 KB (index-space chord a',b')

__device__ inline unsigned short f2bf(float f) {
  union { float f; unsigned u; } v; v.f = f;
  unsigned r = v.u + 0x7FFFu + ((v.u >> 16) & 1u);
  return (unsigned short)(r >> 16);
}

__device__ inline void gload16(const void* g, void* l) {
  __builtin_amdgcn_global_load_lds(
      (const __attribute__((address_space(1))) void*)g,
      (__attribute__((address_space(3))) void*)l, 16, 0, 0);
}

// XOR-swizzled LDS read (k_proj GEMM tiles): 128B rows, slot ^ (row&7)
__device__ inline bf16x8 lds_read_swz(const unsigned short* base, int row, int byteoff) {
  int addr = row * 128 + (byteoff ^ ((row & 7) << 4));
  return *(const bf16x8*)((const char*)base + addr);
}

__device__ inline float expmlp_exact(float t, const float* __restrict__ w1,
                                     const float* __restrict__ b1,
                                     const float* __restrict__ w2, float b2) {
  float a = b2;
#pragma unroll
  for (int n = 0; n < NE_; n++) a += w2[n] * fmaxf(t * w1[n] + b1[n], 0.0f);
  return a;
}

// ---------------------------------------------------------------------------
// Kernel 1: Xsum = sum_t sx[t] (f32->bf16, nt loads), Wq/Wk casts, chord LUT.
__global__ __launch_bounds__(256) void k_pre(
    const float* __restrict__ sx, const float* __restrict__ wq,
    const float* __restrict__ wk, const float* __restrict__ ew1,
    const float* __restrict__ eb1, const float* __restrict__ ew2,
    const float* __restrict__ eb2p,
    unsigned short* __restrict__ xs, unsigned short* __restrict__ wqb,
    unsigned short* __restrict__ wkb, float2* __restrict__ lut) {
  int bx = blockIdx.x, tid = threadIdx.x;
  if (bx < 2048) {
    size_t i = ((size_t)bx * 256 + tid) * 4;
    f32x4 a = __builtin_nontemporal_load((const f32x4*)(sx + i));
#pragma unroll
    for (int t = 1; t < T_; t++) {
      f32x4 v = __builtin_nontemporal_load((const f32x4*)(sx + (size_t)t * 2097152 + i));
      a += v;
    }
    ushort4 o; o.x = f2bf(a[0]); o.y = f2bf(a[1]); o.z = f2bf(a[2]); o.w = f2bf(a[3]);
    *(ushort4*)(xs + i) = o;
  } else if (bx < 2560) {
    const float* src = (bx < 2304) ? wq : wk;
    unsigned short* dst = (bx < 2304) ? wqb : wkb;
    int base = (bx < 2304) ? 2048 : 2304;
    size_t i = ((size_t)(bx - base) * 256 + tid) * 4;
    float4 a = *(const float4*)(src + i);
    ushort4 o; o.x = f2bf(a.x); o.y = f2bf(a.y); o.z = f2bf(a.z); o.w = f2bf(a.w);
    *(ushort4*)(dst + i) = o;
  } else {
    // index-space chord LUT: xu(u) = a'*u + b' on bucket i (u in [i, i+1]);
    // a' = f(t_{i+1})-f(t_i), b' = f(t_i) - a'*i. Edges shared -> continuity.
    int i = (bx - 2560) * 256 + tid;
    if (i < LUT_N) {
      float b2 = eb2p[0];
      float tl = fmaf((float)i, LUT_W, LUT_LO);
      float th = fmaf((float)(i + 1), LUT_W, LUT_LO);
      float el = expmlp_exact(tl, ew1, eb1, ew2, b2);
      float eh = expmlp_exact(th, ew1, eb1, ew2, b2);
      float ap = eh - el;
      float bp = fmaf(-ap, (float)i, el);
      lut[i] = make_float2(ap, bp);
    }
  }
}

// ---------------------------------------------------------------------------
// Kernel 2: Y = Xsum(4096x512) @ W^T + 8*bias -> bf16 frag-order layout.
// z=0 (Q) additionally scaled by 1/64.  grid (64,4,2) = 512 blocks
// (2 blocks/CU), 256 thr, 64x128 tile: 4 waves of 32x64. LDS 24KB.
// Output restaged via LDS (reuses Bs) -> coalesced 16B stores.
__global__ __launch_bounds__(256, 2) void k_proj(
    const unsigned short* __restrict__ xs, const unsigned short* __restrict__ wb,
    const float* __restrict__ bq, const float* __restrict__ bk,
    unsigned short* __restrict__ outb) {
  __shared__ unsigned short As[64 * 64];    // 8 KB
  __shared__ unsigned short Bs[128 * 64];   // 16 KB (reused as Os)
  int tid = threadIdx.x;
  int lane = tid & 63, w = tid >> 6;
  int r0 = blockIdx.x * 64;
  int c0 = blockIdx.y * 128;
  int z = blockIdx.z;
  const unsigned short* W = wb + (size_t)z * 262144;
  const float* bias = z ? bk : bq;
  unsigned short* dst = outb + (size_t)z * 2097152;
  float sc = z ? 1.0f : (1.0f / 64.0f);

  int rgrp = lane >> 4, cl = lane & 15;
  int r0w = (w >> 1) * 32, c0w = (w & 1) * 64;

  f32x4 acc[2][4];
  f32x4 zero = {0.f, 0.f, 0.f, 0.f};
#pragma unroll
  for (int m = 0; m < 2; m++)
#pragma unroll
    for (int n = 0; n < 4; n++) acc[m][n] = zero;

  int rl = lane >> 3, slot = lane & 7;

  for (int kt = 0; kt < 8; kt++) {
    int k0 = kt * 64;
#pragma unroll
    for (int i = 0; i < 2; i++) {
      int chunk = w * 2 + i;
      int r = chunk * 8 + rl;
      int sw = (slot ^ (r & 7)) * 8;
      gload16(xs + (size_t)(r0 + r) * 512 + k0 + sw, (char*)As + chunk * 1024);
    }
#pragma unroll
    for (int i = 0; i < 4; i++) {
      int chunk = w * 4 + i;
      int r = chunk * 8 + rl;
      int sw = (slot ^ (r & 7)) * 8;
      gload16(W + (size_t)(c0 + r) * 512 + k0 + sw, (char*)Bs + chunk * 1024);
    }
    __syncthreads();
#pragma unroll
    for (int kb = 0; kb < 2; kb++) {
      bf16x8 af[2], bfr[4];
#pragma unroll
      for (int m = 0; m < 2; m++) af[m] = lds_read_swz(As, r0w + 16 * m + cl, kb * 64 + rgrp * 16);
#pragma unroll
      for (int n = 0; n < 4; n++) bfr[n] = lds_read_swz(Bs, c0w + 16 * n + cl, kb * 64 + rgrp * 16);
#pragma unroll
      for (int m = 0; m < 2; m++)
#pragma unroll
        for (int n = 0; n < 4; n++)
          acc[m][n] = __builtin_amdgcn_mfma_f32_16x16x32_bf16(af[m], bfr[n], acc[m][n], 0, 0, 0);
    }
    __syncthreads();
  }

  // stage: +8*bias, scale, cast -> Os (=Bs) in frag-order
  unsigned short* Os = Bs;
#pragma unroll
  for (int n = 0; n < 4; n++) {
    int cgl = c0w + 16 * n + cl;               // [0,128)
    float bv = 8.0f * bias[c0 + cgl];
    int hl = cgl >> 6, dh = cgl & 63;
    int hh = dh >> 5, rg2 = (dh >> 3) & 3, jj = dh & 7;
#pragma unroll
    for (int m = 0; m < 2; m++) {
#pragma unroll
      for (int j = 0; j < 4; j++) {
        int rgl = r0w + 16 * m + rgrp * 4 + j;  // [0,64)
        int b = rgl & 7, clsl = rgl >> 3;       // [0,8)
        Os[((((b * 2 + hl) * 2 + hh) * 4 + rg2) * 8 + clsl) * 8 + jj] =
            f2bf((acc[m][n][j] + bv) * sc);
      }
    }
  }
  __syncthreads();

  // coalesced store: 1024 x 16B units
  int cb = blockIdx.x >> 1;
  int clsbase = (blockIdx.x & 1) * 8;
  int h0 = c0 >> 6;
#pragma unroll
  for (int i2 = 0; i2 < 4; i2++) {
    int unit = i2 * 256 + tid;                  // [b:3][hl:1][hh:1][rg2:2][clsl:3]
    int clsl = unit & 7, rg2 = (unit >> 3) & 3, hh = (unit >> 5) & 1;
    int hl = (unit >> 6) & 1, b = unit >> 7;
    int bh = b * 8 + h0 + hl;
    size_t du = ((size_t)((bh * 32 + cb) * 2 + hh)) * 512 + (rg2 * 16 + clsbase + clsl) * 8;
    *(u32x4*)(dst + du) = *(const u32x4*)(Os + unit * 8);
  }
}

// ---------------------------------------------------------------------------
// Kernel 3: per block: TWO consecutive 16-row q-blocks of one bh (unroll-1
// loop). P^T tiles via mfma(K, Q), chord LUT epilogue, f32x4 nt stores.
// grid 1024 x 256 thr (4 waves); wave w = 128 k-col strip, acc[8].
// launch_bounds(256,4): 128-reg budget, PROVEN no-spill envelope.
// s_part double-buffered -> 3 barriers per 2 q-blocks. XCD-chunked blockIdx.
__global__ __launch_bounds__(256, 4) void k_attn(
    const unsigned short* __restrict__ qb, const unsigned short* __restrict__ kb,
    const float2* __restrict__ lutg,
    const float* __restrict__ iw1, const float* __restrict__ ib1,
    const float* __restrict__ iw2, const float* __restrict__ ib2p,
    float* __restrict__ out) {
  __shared__ float2 Lut[LUT_N];   // 16 KB
  __shared__ float s_part[2][4][16];

  int tid = threadIdx.x;
  int lane = tid & 63, w = tid >> 6;   // w = 128-k-col strip
  int i = blockIdx.x;
  int xcd = i & 7, j2 = i >> 3;        // j2 in [0,128)
  int bh = xcd * 8 + (j2 >> 4);
  int rb0 = (j2 & 15) * 2;             // first of two consecutive q-blocks
  int rgrp = lane >> 4, cl = lane & 15;

  // stage LUT once per block: 16 KB via gload16 (4 waves x 4 chunks of 1KB);
  // published by the iter-0 barrier AFTER the MFMA phase.
#pragma unroll
  for (int c = 0; c < 4; c++) {
    int chunk = w * 4 + c;
    gload16((const char*)lutg + chunk * 1024 + lane * 16, (char*)Lut + chunk * 1024);
  }

  const char* Kbase = (const char*)kb + (size_t)(bh * 32) * 2048;
  const float C0 = -LUT_LO * LUT_INVW;
  float b2 = ib2p[0];
  f32x4 zero = {0.f, 0.f, 0.f, 0.f};

#pragma unroll 1
  for (int it = 0; it < 2; ++it) {
    int rb = rb0 + it;
    // Q fragments (B-operand) for this q-block's 16 rows (1KB coalesced)
    const char* Qb = (const char*)qb + (size_t)((bh * 32 + rb) * 2) * 1024;
    bf16x8 qF0 = *(const bf16x8*)(Qb + lane * 16);
    bf16x8 qF1 = *(const bf16x8*)(Qb + 1024 + lane * 16);

    // tmax from k-block 0: D[col=q=cl, row=k]; P[0][q] in lane q, reg 0
    float tm1;
    {
      bf16x8 k0 = *(const bf16x8*)(Kbase + lane * 16);
      bf16x8 k1 = *(const bf16x8*)(Kbase + 1024 + lane * 16);
      f32x4 p0 = __builtin_amdgcn_mfma_f32_16x16x32_bf16(k0, qF0, zero, 0, 0, 0);
      p0 = __builtin_amdgcn_mfma_f32_16x16x32_bf16(k1, qF1, p0, 0, 0, 0);
      tm1 = __shfl(p0[0], cl) - 1.0f;
    }

    f32x4 acc[8];
#pragma unroll
    for (int f = 0; f < 8; f++) {
      const char* Kb = Kbase + (size_t)(w * 8 + f) * 2048;
      bf16x8 k0 = *(const bf16x8*)(Kb + lane * 16);
      bf16x8 k1 = *(const bf16x8*)(Kb + 1024 + lane * 16);
      acc[f] = __builtin_amdgcn_mfma_f32_16x16x32_bf16(k0, qF0, zero, 0, 0, 0);
      acc[f] = __builtin_amdgcn_mfma_f32_16x16x32_bf16(k1, qF1, acc[f], 0, 0, 0);
    }

    if (it == 0) __syncthreads();  // LUT publish (uniform branch)

    // u0 = p*INVW + cj; u0>0 <=> tp>-20; u = clamp(u0,0,N); xu = a'*u + b'
    float cj = fmaf(-tm1, LUT_INVW, C0);
    float rowsum = 0.0f;
#pragma unroll
    for (int f = 0; f < 8; f++) {
#pragma unroll
      for (int j = 0; j < 4; j++) {
        float u0 = fmaf(acc[f][j], LUT_INVW, cj);
        float u = fminf(fmaxf(u0, 0.0f), (float)LUT_N);    // v_med3
        int bi = (int)u;
        bi = min(bi, LUT_N - 1);
        float2 ab = Lut[bi];
        float xu = fmaf(ab.x, u, ab.y);
        xu = (u0 > 0.0f) ? xu : 0.0f;
        acc[f][j] = xu;
        rowsum += xu;
      }
    }

    // lanes {cl, cl+16, cl+32, cl+48} share q-row cl
    rowsum += __shfl_xor(rowsum, 16);
    rowsum += __shfl_xor(rowsum, 32);
    if (lane < 16) s_part[it][w][lane] = rowsum;
    __syncthreads();

    float part = s_part[it][0][cl] + s_part[it][1][cl] +
                 s_part[it][2][cl] + s_part[it][3][cl];

    // n-distributed inv-MLP: lane covers 16 n-terms (chunk = rgrp) of row cl
    float a = 0.0f;
#pragma unroll
    for (int nn = 0; nn < 16; nn++) {
      int n = rgrp * 16 + nn;
      a += iw2[n] * fmaxf(part * iw1[n] + ib1[n], 0.0f);
    }
    a += __shfl_xor(a, 16);
    a += __shfl_xor(a, 32);
    float pinv = a + b2;
    float pp2 = part * pinv;
    float bb = 0.0f;
#pragma unroll
    for (int nn = 0; nn < 16; nn++) {
      int n = rgrp * 16 + nn;
      bb += iw2[n] * fmaxf(pp2 * iw1[n] + ib1[n], 0.0f);
    }
    bb += __shfl_xor(bb, 16);
    bb += __shfl_xor(bb, 32);
    float pinv2 = bb + b2;
    float fac = (pp2 > 1.5f) ? pinv * pinv2 : pinv;

    // f32x4 nt stores: row = q = cl, cols w*128 + f*16 + rgrp*4
    float* outb = out + ((size_t)(bh * 512 + rb * 16 + cl)) * 512 + w * 128 + rgrp * 4;
#pragma unroll
    for (int f = 0; f < 8; f++) {
      f32x4 v;
#pragma unroll
      for (int j = 0; j < 4; j++) v[j] = acc[f][j] * fac;
      __builtin_nontemporal_store(v, (f32x4*)(outb + f * 16));
    }
  }
}

extern "C" void kernel_launch(void* const* d_in, const int* in_sizes, int n_in,
                              void* d_out, int out_size, void* d_ws, size_t ws_size,
                              hipStream_t stream) {
  (void)in_sizes; (void)n_in; (void)out_size; (void)ws_size;
  const float* sx  = (const float*)d_in[0];
  const float* wq  = (const float*)d_in[1];
  const float* wk  = (const float*)d_in[2];
  const float* bq  = (const float*)d_in[3];
  const float* bk  = (const float*)d_in[4];
  const float* ew1 = (const float*)d_in[5];
  const float* eb1 = (const float*)d_in[6];
  const float* ew2 = (const float*)d_in[7];
  const float* eb2 = (const float*)d_in[8];
  const float* iw1 = (const float*)d_in[9];
  const float* ib1 = (const float*)d_in[10];
  const float* iw2 = (const float*)d_in[11];
  const float* ib2 = (const float*)d_in[12];
  unsigned short* wsu = (unsigned short*)d_ws;
  float2* lut = (float2*)(wsu + LUT_OFF);
  float* out = (float*)d_out;

  k_pre<<<2568, 256, 0, stream>>>(sx, wq, wk, ew1, eb1, ew2, eb2,
                                  wsu + XS_OFF, wsu + WQ_OFF, wsu + WK_OFF, lut);
  k_proj<<<dim3(64, 4, 2), 256, 0, stream>>>(wsu + XS_OFF, wsu + WQ_OFF, bq, bk, wsu + QB_OFF);
  k_attn<<<1024, 256, 0, stream>>>(wsu + QB_OFF, wsu + KB_OFF, lut,
                                   iw1, ib1, iw2, ib2, out);
}

// Round 18
// 54.251 us; speedup vs baseline: 1.5326x; 1.2817x over previous
//
#include <hip/hip_runtime.h>

// Shapes (fixed): T=8, S=512, B=8, D=512, H=8, hd=64, BH=64, NE=32, NI=64.
// out: (64, 512, 512) f32.
//
// Math reduction: sum_p telescopes to (sum_t Q_t)(sum_t K_t)^T * scale, so
//   p = (Xsum@Wq^T + 8 bq)(Xsum@Wk^T + 8 bk)^T / 64   (per bh batch, hd=64)
// The 1/64 is folded into Q at projection time.
//
// Q/K are stored in MFMA-FRAGMENT ORDER: [bh][blk16][half][lane][16B], so
// k_attn operand loads are fully-coalesced 1KB dwordx4 reads. The SAME
// layout serves both A- and B-operands.
//
// k_attn computes P^T tiles: mfma(A=K_block, B=Q) -> D[col=q=lane&15,
// row=k=(lane>>4)*4+j]. Each lane holds 4 CONSECUTIVE k for one q-row:
// f32x4 nt stores, scalar tm1/cj/rowsum, lane-local n-distributed fac.
//
// EXACT REVERT to the R15 kernel (54.0us, best measured; clean counters).
// R16/R17 proved the 2-q-block amortization loop spills at ANY bound
// (hidden cross-iteration live state; SGPR collapse 112->32). One q-block
// per block, (256,4), is the stable optimum of this structure.
//
// REGISTER RULE (R4/R6/R8/R14/R16/R17): VGPR+AGPR one budget; this kernel
// family is clean ONLY at acc[8], one q-block, launch_bounds(256,4).

#define T_  8
#define NE_ 32
#define NI_ 64

#define LUT_N   2048
#define LUT_LO  -20.0f
#define LUT_HI  3.0f
#define LUT_INVW (LUT_N / (LUT_HI - LUT_LO))     // 2048/23
#define LUT_W    ((LUT_HI - LUT_LO) / LUT_N)

typedef __attribute__((ext_vector_type(8))) short bf16x8;
typedef __attribute__((ext_vector_type(4))) float f32x4;
typedef __attribute__((ext_vector_type(4))) unsigned int u32x4;

// workspace layout, in ushort elements
#define XS_OFF 0u        // Xsum bf16 (4096 x 512)
#define WQ_OFF 2097152u  // Wq bf16 (512 x 512)
#define WK_OFF 2359296u  // Wk bf16
#define QB_OFF 2621440u  // Q bf16 frag-order (64*32*2*1024B), pre-scaled 1/64
#define KB_OFF 4718592u  // K bf16 frag-order
#define LUT_OFF 6815744u // float2 lut[2048] = 16 KB (index-space chord a',b')

__device__ inline unsigned short f2bf(float f) {
  union { float f; unsigned u; } v; v.f = f;
  unsigned r = v.u + 0x7FFFu + ((v.u >> 16) & 1u);
  return (unsigned short)(r >> 16);
}

__device__ inline void gload16(const void* g, void* l) {
  __builtin_amdgcn_global_load_lds(
      (const __attribute__((address_space(1))) void*)g,
      (__attribute__((address_space(3))) void*)l, 16, 0, 0);
}

// XOR-swizzled LDS read (k_proj GEMM tiles): 128B rows, slot ^ (row&7)
__device__ inline bf16x8 lds_read_swz(const unsigned short* base, int row, int byteoff) {
  int addr = row * 128 + (byteoff ^ ((row & 7) << 4));
  return *(const bf16x8*)((const char*)base + addr);
}

__device__ inline float expmlp_exact(float t, const float* __restrict__ w1,
                                     const float* __restrict__ b1,
                                     const float* __restrict__ w2, float b2) {
  float a = b2;
#pragma unroll
  for (int n = 0; n < NE_; n++) a += w2[n] * fmaxf(t * w1[n] + b1[n], 0.0f);
  return a;
}

// ---------------------------------------------------------------------------
// Kernel 1: Xsum = sum_t sx[t] (f32->bf16, nt loads), Wq/Wk casts, chord LUT.
__global__ __launch_bounds__(256) void k_pre(
    const float* __restrict__ sx, const float* __restrict__ wq,
    const float* __restrict__ wk, const float* __restrict__ ew1,
    const float* __restrict__ eb1, const float* __restrict__ ew2,
    const float* __restrict__ eb2p,
    unsigned short* __restrict__ xs, unsigned short* __restrict__ wqb,
    unsigned short* __restrict__ wkb, float2* __restrict__ lut) {
  int bx = blockIdx.x, tid = threadIdx.x;
  if (bx < 2048) {
    size_t i = ((size_t)bx * 256 + tid) * 4;
    f32x4 a = __builtin_nontemporal_load((const f32x4*)(sx + i));
#pragma unroll
    for (int t = 1; t < T_; t++) {
      f32x4 v = __builtin_nontemporal_load((const f32x4*)(sx + (size_t)t * 2097152 + i));
      a += v;
    }
    ushort4 o; o.x = f2bf(a[0]); o.y = f2bf(a[1]); o.z = f2bf(a[2]); o.w = f2bf(a[3]);
    *(ushort4*)(xs + i) = o;
  } else if (bx < 2560) {
    const float* src = (bx < 2304) ? wq : wk;
    unsigned short* dst = (bx < 2304) ? wqb : wkb;
    int base = (bx < 2304) ? 2048 : 2304;
    size_t i = ((size_t)(bx - base) * 256 + tid) * 4;
    float4 a = *(const float4*)(src + i);
    ushort4 o; o.x = f2bf(a.x); o.y = f2bf(a.y); o.z = f2bf(a.z); o.w = f2bf(a.w);
    *(ushort4*)(dst + i) = o;
  } else {
    // index-space chord LUT: xu(u) = a'*u + b' on bucket i (u in [i, i+1]);
    // a' = f(t_{i+1})-f(t_i), b' = f(t_i) - a'*i. Edges shared -> continuity.
    int i = (bx - 2560) * 256 + tid;
    if (i < LUT_N) {
      float b2 = eb2p[0];
      float tl = fmaf((float)i, LUT_W, LUT_LO);
      float th = fmaf((float)(i + 1), LUT_W, LUT_LO);
      float el = expmlp_exact(tl, ew1, eb1, ew2, b2);
      float eh = expmlp_exact(th, ew1, eb1, ew2, b2);
      float ap = eh - el;
      float bp = fmaf(-ap, (float)i, el);
      lut[i] = make_float2(ap, bp);
    }
  }
}

// ---------------------------------------------------------------------------
// Kernel 2: Y = Xsum(4096x512) @ W^T + 8*bias -> bf16 frag-order layout.
// z=0 (Q) additionally scaled by 1/64.  grid (64,4,2) = 512 blocks
// (2 blocks/CU), 256 thr, 64x128 tile: 4 waves of 32x64. LDS 24KB.
// Output restaged via LDS (reuses Bs) -> coalesced 16B stores.
__global__ __launch_bounds__(256, 2) void k_proj(
    const unsigned short* __restrict__ xs, const unsigned short* __restrict__ wb,
    const float* __restrict__ bq, const float* __restrict__ bk,
    unsigned short* __restrict__ outb) {
  __shared__ unsigned short As[64 * 64];    // 8 KB
  __shared__ unsigned short Bs[128 * 64];   // 16 KB (reused as Os)
  int tid = threadIdx.x;
  int lane = tid & 63, w = tid >> 6;
  int r0 = blockIdx.x * 64;
  int c0 = blockIdx.y * 128;
  int z = blockIdx.z;
  const unsigned short* W = wb + (size_t)z * 262144;
  const float* bias = z ? bk : bq;
  unsigned short* dst = outb + (size_t)z * 2097152;
  float sc = z ? 1.0f : (1.0f / 64.0f);

  int rgrp = lane >> 4, cl = lane & 15;
  int r0w = (w >> 1) * 32, c0w = (w & 1) * 64;

  f32x4 acc[2][4];
  f32x4 zero = {0.f, 0.f, 0.f, 0.f};
#pragma unroll
  for (int m = 0; m < 2; m++)
#pragma unroll
    for (int n = 0; n < 4; n++) acc[m][n] = zero;

  int rl = lane >> 3, slot = lane & 7;

  for (int kt = 0; kt < 8; kt++) {
    int k0 = kt * 64;
#pragma unroll
    for (int i = 0; i < 2; i++) {
      int chunk = w * 2 + i;
      int r = chunk * 8 + rl;
      int sw = (slot ^ (r & 7)) * 8;
      gload16(xs + (size_t)(r0 + r) * 512 + k0 + sw, (char*)As + chunk * 1024);
    }
#pragma unroll
    for (int i = 0; i < 4; i++) {
      int chunk = w * 4 + i;
      int r = chunk * 8 + rl;
      int sw = (slot ^ (r & 7)) * 8;
      gload16(W + (size_t)(c0 + r) * 512 + k0 + sw, (char*)Bs + chunk * 1024);
    }
    __syncthreads();
#pragma unroll
    for (int kb = 0; kb < 2; kb++) {
      bf16x8 af[2], bfr[4];
#pragma unroll
      for (int m = 0; m < 2; m++) af[m] = lds_read_swz(As, r0w + 16 * m + cl, kb * 64 + rgrp * 16);
#pragma unroll
      for (int n = 0; n < 4; n++) bfr[n] = lds_read_swz(Bs, c0w + 16 * n + cl, kb * 64 + rgrp * 16);
#pragma unroll
      for (int m = 0; m < 2; m++)
#pragma unroll
        for (int n = 0; n < 4; n++)
          acc[m][n] = __builtin_amdgcn_mfma_f32_16x16x32_bf16(af[m], bfr[n], acc[m][n], 0, 0, 0);
    }
    __syncthreads();
  }

  // stage: +8*bias, scale, cast -> Os (=Bs) in frag-order
  unsigned short* Os = Bs;
#pragma unroll
  for (int n = 0; n < 4; n++) {
    int cgl = c0w + 16 * n + cl;               // [0,128)
    float bv = 8.0f * bias[c0 + cgl];
    int hl = cgl >> 6, dh = cgl & 63;
    int hh = dh >> 5, rg2 = (dh >> 3) & 3, jj = dh & 7;
#pragma unroll
    for (int m = 0; m < 2; m++) {
#pragma unroll
      for (int j = 0; j < 4; j++) {
        int rgl = r0w + 16 * m + rgrp * 4 + j;  // [0,64)
        int b = rgl & 7, clsl = rgl >> 3;       // [0,8)
        Os[((((b * 2 + hl) * 2 + hh) * 4 + rg2) * 8 + clsl) * 8 + jj] =
            f2bf((acc[m][n][j] + bv) * sc);
      }
    }
  }
  __syncthreads();

  // coalesced store: 1024 x 16B units
  int cb = blockIdx.x >> 1;
  int clsbase = (blockIdx.x & 1) * 8;
  int h0 = c0 >> 6;
#pragma unroll
  for (int i2 = 0; i2 < 4; i2++) {
    int unit = i2 * 256 + tid;                  // [b:3][hl:1][hh:1][rg2:2][clsl:3]
    int clsl = unit & 7, rg2 = (unit >> 3) & 3, hh = (unit >> 5) & 1;
    int hl = (unit >> 6) & 1, b = unit >> 7;
    int bh = b * 8 + h0 + hl;
    size_t du = ((size_t)((bh * 32 + cb) * 2 + hh)) * 512 + (rg2 * 16 + clsbase + clsl) * 8;
    *(u32x4*)(dst + du) = *(const u32x4*)(Os + unit * 8);
  }
}

// ---------------------------------------------------------------------------
// Kernel 3: per (16-row q-block rb, bh): P^T tiles via mfma(K, Q), chord LUT
// epilogue, f32x4 stores. grid 2048 x 256 thr (4 waves); wave w = 128 k-col
// strip, acc[8]. launch_bounds(256,4): proven no-spill. XCD-chunked blockIdx.
__global__ __launch_bounds__(256, 4) void k_attn(
    const unsigned short* __restrict__ qb, const unsigned short* __restrict__ kb,
    const float2* __restrict__ lutg,
    const float* __restrict__ iw1, const float* __restrict__ ib1,
    const float* __restrict__ iw2, const float* __restrict__ ib2p,
    float* __restrict__ out) {
  __shared__ float2 Lut[LUT_N];   // 16 KB
  __shared__ float s_part[4][16];

  int tid = threadIdx.x;
  int lane = tid & 63, w = tid >> 6;   // w = 128-k-col strip
  int i = blockIdx.x;
  int xcd = i & 7, j2 = i >> 3;        // j2 in [0,256)
  int bh = xcd * 8 + (j2 >> 5);
  int rb = j2 & 31;                    // 16-row q-block
  int rgrp = lane >> 4, cl = lane & 15;

  // stage LUT: 16 KB via gload16 (4 waves x 4 chunks of 1KB); published by
  // the barrier AFTER the MFMA phase (loads land under compute).
#pragma unroll
  for (int c = 0; c < 4; c++) {
    int chunk = w * 4 + c;
    gload16((const char*)lutg + chunk * 1024 + lane * 16, (char*)Lut + chunk * 1024);
  }

  // Q fragments (B-operand) for this block's 16 q-rows (1KB coalesced each)
  const char* Qb = (const char*)qb + (size_t)((bh * 32 + rb) * 2) * 1024;
  bf16x8 qF0 = *(const bf16x8*)(Qb + lane * 16);
  bf16x8 qF1 = *(const bf16x8*)(Qb + 1024 + lane * 16);

  const char* Kbase = (const char*)kb + (size_t)(bh * 32) * 2048;
  f32x4 zero = {0.f, 0.f, 0.f, 0.f};

  // tmax from k-block 0: D[col=q=cl, row=k=rgrp*4+j]; P[0][q] lives in
  // lane q (rgrp 0), reg 0 -> scalar broadcast per lane's own row.
  float tm1;
  {
    bf16x8 k0 = *(const bf16x8*)(Kbase + lane * 16);
    bf16x8 k1 = *(const bf16x8*)(Kbase + 1024 + lane * 16);
    f32x4 p0 = __builtin_amdgcn_mfma_f32_16x16x32_bf16(k0, qF0, zero, 0, 0, 0);
    p0 = __builtin_amdgcn_mfma_f32_16x16x32_bf16(k1, qF1, p0, 0, 0, 0);
    tm1 = __shfl(p0[0], cl) - 1.0f;
  }

  f32x4 acc[8];
#pragma unroll
  for (int f = 0; f < 8; f++) {
    const char* Kb = Kbase + (size_t)(w * 8 + f) * 2048;
    bf16x8 k0 = *(const bf16x8*)(Kb + lane * 16);
    bf16x8 k1 = *(const bf16x8*)(Kb + 1024 + lane * 16);
    acc[f] = __builtin_amdgcn_mfma_f32_16x16x32_bf16(k0, qF0, zero, 0, 0, 0);
    acc[f] = __builtin_amdgcn_mfma_f32_16x16x32_bf16(k1, qF1, acc[f], 0, 0, 0);
  }

  __syncthreads();  // LUT visible (gloads landed during MFMA phase)

  // u0 = p*INVW + cj; u0>0 <=> tp>-20; u = clamp(u0,0,N); xu = a'*u + b'
  const float C0 = -LUT_LO * LUT_INVW;
  float cj = fmaf(-tm1, LUT_INVW, C0);

  float rowsum = 0.0f;
#pragma unroll
  for (int f = 0; f < 8; f++) {
#pragma unroll
    for (int j = 0; j < 4; j++) {
      float u0 = fmaf(acc[f][j], LUT_INVW, cj);
      float u = fminf(fmaxf(u0, 0.0f), (float)LUT_N);    // v_med3, [0, 2048]
      int bi = (int)u;
      bi = min(bi, LUT_N - 1);
      float2 ab = Lut[bi];
      float xu = fmaf(ab.x, u, ab.y);
      xu = (u0 > 0.0f) ? xu : 0.0f;
      acc[f][j] = xu;
      rowsum += xu;
    }
  }

  // row partial sums: lanes {cl, cl+16, cl+32, cl+48} share q-row cl
  rowsum += __shfl_xor(rowsum, 16);
  rowsum += __shfl_xor(rowsum, 32);
  if (lane < 16) s_part[w][lane] = rowsum;
  __syncthreads();

  float part = s_part[0][cl] + s_part[1][cl] + s_part[2][cl] + s_part[3][cl];

  // n-distributed inv-MLP: lane covers 16 n-terms (chunk = rgrp) of row cl;
  // reduce across the 4 chunks via shfl_xor(16/32). Lane-local fac, no LDS.
  float b2 = ib2p[0];
  float a = 0.0f;
#pragma unroll
  for (int nn = 0; nn < 16; nn++) {
    int n = rgrp * 16 + nn;
    a += iw2[n] * fmaxf(part * iw1[n] + ib1[n], 0.0f);
  }
  a += __shfl_xor(a, 16);
  a += __shfl_xor(a, 32);
  float pinv = a + b2;
  float pp2 = part * pinv;
  float b = 0.0f;
#pragma unroll
  for (int nn = 0; nn < 16; nn++) {
    int n = rgrp * 16 + nn;
    b += iw2[n] * fmaxf(pp2 * iw1[n] + ib1[n], 0.0f);
  }
  b += __shfl_xor(b, 16);
  b += __shfl_xor(b, 32);
  float pinv2 = b + b2;
  float fac = (pp2 > 1.5f) ? pinv * pinv2 : pinv;

  // f32x4 nt stores: row = q = cl, cols w*128 + f*16 + rgrp*4 + j
  float* outb = out + ((size_t)(bh * 512 + rb * 16 + cl)) * 512 + w * 128 + rgrp * 4;
#pragma unroll
  for (int f = 0; f < 8; f++) {
    f32x4 v;
#pragma unroll
    for (int j = 0; j < 4; j++) v[j] = acc[f][j] * fac;
    __builtin_nontemporal_store(v, (f32x4*)(outb + f * 16));
  }
}

extern "C" void kernel_launch(void* const* d_in, const int* in_sizes, int n_in,
                              void* d_out, int out_size, void* d_ws, size_t ws_size,
                              hipStream_t stream) {
  (void)in_sizes; (void)n_in; (void)out_size; (void)ws_size;
  const float* sx  = (const float*)d_in[0];
  const float* wq  = (const float*)d_in[1];
  const float* wk  = (const float*)d_in[2];
  const float* bq  = (const float*)d_in[3];
  const float* bk  = (const float*)d_in[4];
  const float* ew1 = (const float*)d_in[5];
  const float* eb1 = (const float*)d_in[6];
  const float* ew2 = (const float*)d_in[7];
  const float* eb2 = (const float*)d_in[8];
  const float* iw1 = (const float*)d_in[9];
  const float* ib1 = (const float*)d_in[10];
  const float* iw2 = (const float*)d_in[11];
  const float* ib2 = (const float*)d_in[12];
  unsigned short* wsu = (unsigned short*)d_ws;
  float2* lut = (float2*)(wsu + LUT_OFF);
  float* out = (float*)d_out;

  k_pre<<<2568, 256, 0, stream>>>(sx, wq, wk, ew1, eb1, ew2, eb2,
                                  wsu + XS_OFF, wsu + WQ_OFF, wsu + WK_OFF, lut);
  k_proj<<<dim3(64, 4, 2), 256, 0, stream>>>(wsu + XS_OFF, wsu + WQ_OFF, bq, bk, wsu + QB_OFF);
  k_attn<<<2048, 256, 0, stream>>>(wsu + QB_OFF, wsu + KB_OFF, lut,
                                   iw1, ib1, iw2, ib2, out);
}

// Round 19
// 53.797 us; speedup vs baseline: 1.5456x; 1.0084x over previous
//
#include <hip/hip_runtime.h>

// Shapes (fixed): T=8, S=512, B=8, D=512, H=8, hd=64, BH=64, NE=32, NI=64.
// out: (64, 512, 512) f32.
//
// Math reduction: sum_p telescopes to (sum_t Q_t)(sum_t K_t)^T * scale, so
//   p = (Xsum@Wq^T + 8 bq)(Xsum@Wk^T + 8 bk)^T / 64   (per bh batch, hd=64)
// The 1/64 is folded into Q at projection time.
//
// Q/K are stored in MFMA-FRAGMENT ORDER: [bh][blk16][half][lane][16B], so
// k_attn operand loads are fully-coalesced 1KB dwordx4 reads. The SAME
// layout serves both A- and B-operands.
//
// k_attn computes P^T tiles: mfma(A=K_block, B=Q) -> D[col=q=lane&15,
// row=k=(lane>>4)*4+j]. Each lane holds 4 CONSECUTIVE k for one q-row:
// f32x4 nt stores, scalar tm1/cj/rowsum, lane-local n-distributed fac.
//
// R18->R19 (final probe, two micro-tweaks on the frozen R15 structure):
// (a) LUT_N 2048->1024 (8KB): halves the staging tail the pre-epilogue
//     barrier drains (MFMA phase is too short to hide 16KB); chord error
//     ~0.06 abs, 6 orders below threshold. (b) s_setprio(1/0) around the
//     MFMA cluster (T5; blocks are desynchronized -> phase diversity).
//
// REGISTER RULE (R4/R6/R8/R14/R16/R17): VGPR+AGPR one budget; this kernel
// family is clean ONLY at acc[8], one q-block, launch_bounds(256,4).

#define T_  8
#define NE_ 32
#define NI_ 64

#define LUT_N   1024
#define LUT_LO  -20.0f
#define LUT_HI  3.0f
#define LUT_INVW (LUT_N / (LUT_HI - LUT_LO))     // 1024/23
#define LUT_W    ((LUT_HI - LUT_LO) / LUT_N)

typedef __attribute__((ext_vector_type(8))) short bf16x8;
typedef __attribute__((ext_vector_type(4))) float f32x4;
typedef __attribute__((ext_vector_type(4))) unsigned int u32x4;

// workspace layout, in ushort elements
#define XS_OFF 0u        // Xsum bf16 (4096 x 512)
#define WQ_OFF 2097152u  // Wq bf16 (512 x 512)
#define WK_OFF 2359296u  // Wk bf16
#define QB_OFF 2621440u  // Q bf16 frag-order (64*32*2*1024B), pre-scaled 1/64
#define KB_OFF 4718592u  // K bf16 frag-order
#define LUT_OFF 6815744u // float2 lut[1024] = 8 KB (index-space chord a',b')

__device__ inline unsigned short f2bf(float f) {
  union { float f; unsigned u; } v; v.f = f;
  unsigned r = v.u + 0x7FFFu + ((v.u >> 16) & 1u);
  return (unsigned short)(r >> 16);
}

__device__ inline void gload16(const void* g, void* l) {
  __builtin_amdgcn_global_load_lds(
      (const __attribute__((address_space(1))) void*)g,
      (__attribute__((address_space(3))) void*)l, 16, 0, 0);
}

// XOR-swizzled LDS read (k_proj GEMM tiles): 128B rows, slot ^ (row&7)
__device__ inline bf16x8 lds_read_swz(const unsigned short* base, int row, int byteoff) {
  int addr = row * 128 + (byteoff ^ ((row & 7) << 4));
  return *(const bf16x8*)((const char*)base + addr);
}

__device__ inline float expmlp_exact(float t, const float* __restrict__ w1,
                                     const float* __restrict__ b1,
                                     const float* __restrict__ w2, float b2) {
  float a = b2;
#pragma unroll
  for (int n = 0; n < NE_; n++) a += w2[n] * fmaxf(t * w1[n] + b1[n], 0.0f);
  return a;
}

// ---------------------------------------------------------------------------
// Kernel 1: Xsum = sum_t sx[t] (f32->bf16, nt loads), Wq/Wk casts, chord LUT.
__global__ __launch_bounds__(256) void k_pre(
    const float* __restrict__ sx, const float* __restrict__ wq,
    const float* __restrict__ wk, const float* __restrict__ ew1,
    const float* __restrict__ eb1, const float* __restrict__ ew2,
    const float* __restrict__ eb2p,
    unsigned short* __restrict__ xs, unsigned short* __restrict__ wqb,
    unsigned short* __restrict__ wkb, float2* __restrict__ lut) {
  int bx = blockIdx.x, tid = threadIdx.x;
  if (bx < 2048) {
    size_t i = ((size_t)bx * 256 + tid) * 4;
    f32x4 a = __builtin_nontemporal_load((const f32x4*)(sx + i));
#pragma unroll
    for (int t = 1; t < T_; t++) {
      f32x4 v = __builtin_nontemporal_load((const f32x4*)(sx + (size_t)t * 2097152 + i));
      a += v;
    }
    ushort4 o; o.x = f2bf(a[0]); o.y = f2bf(a[1]); o.z = f2bf(a[2]); o.w = f2bf(a[3]);
    *(ushort4*)(xs + i) = o;
  } else if (bx < 2560) {
    const float* src = (bx < 2304) ? wq : wk;
    unsigned short* dst = (bx < 2304) ? wqb : wkb;
    int base = (bx < 2304) ? 2048 : 2304;
    size_t i = ((size_t)(bx - base) * 256 + tid) * 4;
    float4 a = *(const float4*)(src + i);
    ushort4 o; o.x = f2bf(a.x); o.y = f2bf(a.y); o.z = f2bf(a.z); o.w = f2bf(a.w);
    *(ushort4*)(dst + i) = o;
  } else {
    // index-space chord LUT: xu(u) = a'*u + b' on bucket i (u in [i, i+1]);
    // a' = f(t_{i+1})-f(t_i), b' = f(t_i) - a'*i. Edges shared -> continuity.
    int i = (bx - 2560) * 256 + tid;
    if (i < LUT_N) {
      float b2 = eb2p[0];
      float tl = fmaf((float)i, LUT_W, LUT_LO);
      float th = fmaf((float)(i + 1), LUT_W, LUT_LO);
      float el = expmlp_exact(tl, ew1, eb1, ew2, b2);
      float eh = expmlp_exact(th, ew1, eb1, ew2, b2);
      float ap = eh - el;
      float bp = fmaf(-ap, (float)i, el);
      lut[i] = make_float2(ap, bp);
    }
  }
}

// ---------------------------------------------------------------------------
// Kernel 2: Y = Xsum(4096x512) @ W^T + 8*bias -> bf16 frag-order layout.
// z=0 (Q) additionally scaled by 1/64.  grid (64,4,2) = 512 blocks
// (2 blocks/CU), 256 thr, 64x128 tile: 4 waves of 32x64. LDS 24KB.
// Output restaged via LDS (reuses Bs) -> coalesced 16B stores.
__global__ __launch_bounds__(256, 2) void k_proj(
    const unsigned short* __restrict__ xs, const unsigned short* __restrict__ wb,
    const float* __restrict__ bq, const float* __restrict__ bk,
    unsigned short* __restrict__ outb) {
  __shared__ unsigned short As[64 * 64];    // 8 KB
  __shared__ unsigned short Bs[128 * 64];   // 16 KB (reused as Os)
  int tid = threadIdx.x;
  int lane = tid & 63, w = tid >> 6;
  int r0 = blockIdx.x * 64;
  int c0 = blockIdx.y * 128;
  int z = blockIdx.z;
  const unsigned short* W = wb + (size_t)z * 262144;
  const float* bias = z ? bk : bq;
  unsigned short* dst = outb + (size_t)z * 2097152;
  float sc = z ? 1.0f : (1.0f / 64.0f);

  int rgrp = lane >> 4, cl = lane & 15;
  int r0w = (w >> 1) * 32, c0w = (w & 1) * 64;

  f32x4 acc[2][4];
  f32x4 zero = {0.f, 0.f, 0.f, 0.f};
#pragma unroll
  for (int m = 0; m < 2; m++)
#pragma unroll
    for (int n = 0; n < 4; n++) acc[m][n] = zero;

  int rl = lane >> 3, slot = lane & 7;

  for (int kt = 0; kt < 8; kt++) {
    int k0 = kt * 64;
#pragma unroll
    for (int i = 0; i < 2; i++) {
      int chunk = w * 2 + i;
      int r = chunk * 8 + rl;
      int sw = (slot ^ (r & 7)) * 8;
      gload16(xs + (size_t)(r0 + r) * 512 + k0 + sw, (char*)As + chunk * 1024);
    }
#pragma unroll
    for (int i = 0; i < 4; i++) {
      int chunk = w * 4 + i;
      int r = chunk * 8 + rl;
      int sw = (slot ^ (r & 7)) * 8;
      gload16(W + (size_t)(c0 + r) * 512 + k0 + sw, (char*)Bs + chunk * 1024);
    }
    __syncthreads();
#pragma unroll
    for (int kb = 0; kb < 2; kb++) {
      bf16x8 af[2], bfr[4];
#pragma unroll
      for (int m = 0; m < 2; m++) af[m] = lds_read_swz(As, r0w + 16 * m + cl, kb * 64 + rgrp * 16);
#pragma unroll
      for (int n = 0; n < 4; n++) bfr[n] = lds_read_swz(Bs, c0w + 16 * n + cl, kb * 64 + rgrp * 16);
#pragma unroll
      for (int m = 0; m < 2; m++)
#pragma unroll
        for (int n = 0; n < 4; n++)
          acc[m][n] = __builtin_amdgcn_mfma_f32_16x16x32_bf16(af[m], bfr[n], acc[m][n], 0, 0, 0);
    }
    __syncthreads();
  }

  // stage: +8*bias, scale, cast -> Os (=Bs) in frag-order
  unsigned short* Os = Bs;
#pragma unroll
  for (int n = 0; n < 4; n++) {
    int cgl = c0w + 16 * n + cl;               // [0,128)
    float bv = 8.0f * bias[c0 + cgl];
    int hl = cgl >> 6, dh = cgl & 63;
    int hh = dh >> 5, rg2 = (dh >> 3) & 3, jj = dh & 7;
#pragma unroll
    for (int m = 0; m < 2; m++) {
#pragma unroll
      for (int j = 0; j < 4; j++) {
        int rgl = r0w + 16 * m + rgrp * 4 + j;  // [0,64)
        int b = rgl & 7, clsl = rgl >> 3;       // [0,8)
        Os[((((b * 2 + hl) * 2 + hh) * 4 + rg2) * 8 + clsl) * 8 + jj] =
            f2bf((acc[m][n][j] + bv) * sc);
      }
    }
  }
  __syncthreads();

  // coalesced store: 1024 x 16B units
  int cb = blockIdx.x >> 1;
  int clsbase = (blockIdx.x & 1) * 8;
  int h0 = c0 >> 6;
#pragma unroll
  for (int i2 = 0; i2 < 4; i2++) {
    int unit = i2 * 256 + tid;                  // [b:3][hl:1][hh:1][rg2:2][clsl:3]
    int clsl = unit & 7, rg2 = (unit >> 3) & 3, hh = (unit >> 5) & 1;
    int hl = (unit >> 6) & 1, b = unit >> 7;
    int bh = b * 8 + h0 + hl;
    size_t du = ((size_t)((bh * 32 + cb) * 2 + hh)) * 512 + (rg2 * 16 + clsbase + clsl) * 8;
    *(u32x4*)(dst + du) = *(const u32x4*)(Os + unit * 8);
  }
}

// ---------------------------------------------------------------------------
// Kernel 3: per (16-row q-block rb, bh): P^T tiles via mfma(K, Q), chord LUT
// epilogue, f32x4 stores. grid 2048 x 256 thr (4 waves); wave w = 128 k-col
// strip, acc[8]. launch_bounds(256,4): proven no-spill. XCD-chunked blockIdx.
__global__ __launch_bounds__(256, 4) void k_attn(
    const unsigned short* __restrict__ qb, const unsigned short* __restrict__ kb,
    const float2* __restrict__ lutg,
    const float* __restrict__ iw1, const float* __restrict__ ib1,
    const float* __restrict__ iw2, const float* __restrict__ ib2p,
    float* __restrict__ out) {
  __shared__ float2 Lut[LUT_N];   // 8 KB
  __shared__ float s_part[4][16];

  int tid = threadIdx.x;
  int lane = tid & 63, w = tid >> 6;   // w = 128-k-col strip
  int i = blockIdx.x;
  int xcd = i & 7, j2 = i >> 3;        // j2 in [0,256)
  int bh = xcd * 8 + (j2 >> 5);
  int rb = j2 & 31;                    // 16-row q-block
  int rgrp = lane >> 4, cl = lane & 15;

  // stage LUT: 8 KB via gload16 (4 waves x 2 chunks of 1KB); published by
  // the barrier AFTER the MFMA phase (loads land under compute).
#pragma unroll
  for (int c = 0; c < 2; c++) {
    int chunk = w * 2 + c;
    gload16((const char*)lutg + chunk * 1024 + lane * 16, (char*)Lut + chunk * 1024);
  }

  // Q fragments (B-operand) for this block's 16 q-rows (1KB coalesced each)
  const char* Qb = (const char*)qb + (size_t)((bh * 32 + rb) * 2) * 1024;
  bf16x8 qF0 = *(const bf16x8*)(Qb + lane * 16);
  bf16x8 qF1 = *(const bf16x8*)(Qb + 1024 + lane * 16);

  const char* Kbase = (const char*)kb + (size_t)(bh * 32) * 2048;
  f32x4 zero = {0.f, 0.f, 0.f, 0.f};

  // tmax from k-block 0: D[col=q=cl, row=k=rgrp*4+j]; P[0][q] lives in
  // lane q (rgrp 0), reg 0 -> scalar broadcast per lane's own row.
  float tm1;
  {
    bf16x8 k0 = *(const bf16x8*)(Kbase + lane * 16);
    bf16x8 k1 = *(const bf16x8*)(Kbase + 1024 + lane * 16);
    f32x4 p0 = __builtin_amdgcn_mfma_f32_16x16x32_bf16(k0, qF0, zero, 0, 0, 0);
    p0 = __builtin_amdgcn_mfma_f32_16x16x32_bf16(k1, qF1, p0, 0, 0, 0);
    tm1 = __shfl(p0[0], cl) - 1.0f;
  }

  f32x4 acc[8];
  __builtin_amdgcn_s_setprio(1);
#pragma unroll
  for (int f = 0; f < 8; f++) {
    const char* Kb = Kbase + (size_t)(w * 8 + f) * 2048;
    bf16x8 k0 = *(const bf16x8*)(Kb + lane * 16);
    bf16x8 k1 = *(const bf16x8*)(Kb + 1024 + lane * 16);
    acc[f] = __builtin_amdgcn_mfma_f32_16x16x32_bf16(k0, qF0, zero, 0, 0, 0);
    acc[f] = __builtin_amdgcn_mfma_f32_16x16x32_bf16(k1, qF1, acc[f], 0, 0, 0);
  }
  __builtin_amdgcn_s_setprio(0);

  __syncthreads();  // LUT visible (gloads landed during MFMA phase)

  // u0 = p*INVW + cj; u0>0 <=> tp>-20; u = clamp(u0,0,N); xu = a'*u + b'
  const float C0 = -LUT_LO * LUT_INVW;
  float cj = fmaf(-tm1, LUT_INVW, C0);

  float rowsum = 0.0f;
#pragma unroll
  for (int f = 0; f < 8; f++) {
#pragma unroll
    for (int j = 0; j < 4; j++) {
      float u0 = fmaf(acc[f][j], LUT_INVW, cj);
      float u = fminf(fmaxf(u0, 0.0f), (float)LUT_N);    // v_med3, [0, 1024]
      int bi = (int)u;
      bi = min(bi, LUT_N - 1);
      float2 ab = Lut[bi];
      float xu = fmaf(ab.x, u, ab.y);
      xu = (u0 > 0.0f) ? xu : 0.0f;
      acc[f][j] = xu;
      rowsum += xu;
    }
  }

  // row partial sums: lanes {cl, cl+16, cl+32, cl+48} share q-row cl
  rowsum += __shfl_xor(rowsum, 16);
  rowsum += __shfl_xor(rowsum, 32);
  if (lane < 16) s_part[w][lane] = rowsum;
  __syncthreads();

  float part = s_part[0][cl] + s_part[1][cl] + s_part[2][cl] + s_part[3][cl];

  // n-distributed inv-MLP: lane covers 16 n-terms (chunk = rgrp) of row cl;
  // reduce across the 4 chunks via shfl_xor(16/32). Lane-local fac, no LDS.
  float b2 = ib2p[0];
  float a = 0.0f;
#pragma unroll
  for (int nn = 0; nn < 16; nn++) {
    int n = rgrp * 16 + nn;
    a += iw2[n] * fmaxf(part * iw1[n] + ib1[n], 0.0f);
  }
  a += __shfl_xor(a, 16);
  a += __shfl_xor(a, 32);
  float pinv = a + b2;
  float pp2 = part * pinv;
  float b = 0.0f;
#pragma unroll
  for (int nn = 0; nn < 16; nn++) {
    int n = rgrp * 16 + nn;
    b += iw2[n] * fmaxf(pp2 * iw1[n] + ib1[n], 0.0f);
  }
  b += __shfl_xor(b, 16);
  b += __shfl_xor(b, 32);
  float pinv2 = b + b2;
  float fac = (pp2 > 1.5f) ? pinv * pinv2 : pinv;

  // f32x4 nt stores: row = q = cl, cols w*128 + f*16 + rgrp*4 + j
  float* outb = out + ((size_t)(bh * 512 + rb * 16 + cl)) * 512 + w * 128 + rgrp * 4;
#pragma unroll
  for (int f = 0; f < 8; f++) {
    f32x4 v;
#pragma unroll
    for (int j = 0; j < 4; j++) v[j] = acc[f][j] * fac;
    __builtin_nontemporal_store(v, (f32x4*)(outb + f * 16));
  }
}

extern "C" void kernel_launch(void* const* d_in, const int* in_sizes, int n_in,
                              void* d_out, int out_size, void* d_ws, size_t ws_size,
                              hipStream_t stream) {
  (void)in_sizes; (void)n_in; (void)out_size; (void)ws_size;
  const float* sx  = (const float*)d_in[0];
  const float* wq  = (const float*)d_in[1];
  const float* wk  = (const float*)d_in[2];
  const float* bq  = (const float*)d_in[3];
  const float* bk  = (const float*)d_in[4];
  const float* ew1 = (const float*)d_in[5];
  const float* eb1 = (const float*)d_in[6];
  const float* ew2 = (const float*)d_in[7];
  const float* eb2 = (const float*)d_in[8];
  const float* iw1 = (const float*)d_in[9];
  const float* ib1 = (const float*)d_in[10];
  const float* iw2 = (const float*)d_in[11];
  const float* ib2 = (const float*)d_in[12];
  unsigned short* wsu = (unsigned short*)d_ws;
  float2* lut = (float2*)(wsu + LUT_OFF);
  float* out = (float*)d_out;

  k_pre<<<2564, 256, 0, stream>>>(sx, wq, wk, ew1, eb1, ew2, eb2,
                                  wsu + XS_OFF, wsu + WQ_OFF, wsu + WK_OFF, lut);
  k_proj<<<dim3(64, 4, 2), 256, 0, stream>>>(wsu + XS_OFF, wsu + WQ_OFF, bq, bk, wsu + QB_OFF);
  k_attn<<<2048, 256, 0, stream>>>(wsu + QB_OFF, wsu + KB_OFF, lut,
                                   iw1, ib1, iw2, ib2, out);
}